// Round 6
// baseline (52.028 us; speedup 1.0000x reference)
//
#include <hip/hip_runtime.h>
#include <hip/hip_bf16.h>

typedef float f32x4 __attribute__((ext_vector_type(4)));

// Fully fused ternary-quant + conv1d, barrier-minimal.
// y[b,l,f] = bias[f] + sum_k wq[k,f] * x[b, l+k-7]   (SAME pad: lo=7, hi=8)
// Grid 2048 = 32 b x 16 groups... (see launch): each block owns 128 consecutive l.
// Thread t: fg = t&63 owns f = 4*fg..4*fg+3 (f32x4 stores, plain — nt was -16%),
// ls = t>>6 staggers l (wave-uniform -> LDS broadcast reads).
// alpha: per-wave butterfly over each lane's 64 loaded weights — bit-identical
// in every wave (same operands, same order; IEEE add commutative) -> NO LDS
// reduce, NO barriers. The single __syncthreads (xs ready) precedes all stores,
// so its implicit vmcnt(0) drains an empty store queue (free). After it, 32
// store iterations run with no barrier -> store pipe never drains mid-kernel.
__global__ __launch_bounds__(256) void ternary_conv1d_fused(
    const float* __restrict__ x,   // (B, L)
    const float* __restrict__ w,   // (16, 256) raw
    const float* __restrict__ bias,// (256)
    float* __restrict__ y,         // (B, L, 256)
    int L) {
    const int t  = threadIdx.x;
    const int fg = t & 63;
    const int ls = t >> 6;
    const int bid = blockIdx.x;
    const int b  = bid >> 6;          // 64 l-groups per batch
    const int g  = bid & 63;
    const int lbase = g * 128;

    __shared__ float xs[144];         // xs[j] = x[b, lbase-7+j], j=0..142

    // ---- stage x window (issue loads first; latency hides under alpha calc) ----
    if (t < 143) {
        int gl = lbase - 7 + t;
        xs[t] = (gl >= 0 && gl < L) ? x[(size_t)b * L + gl] : 0.f;
    }

    // ---- load weights (1KB/wave-instr, L2-hot) + per-lane |w| partial ----
    f32x4 wv[16];
    float s = 0.f;
#pragma unroll
    for (int k = 0; k < 16; ++k) {
        f32x4 v = *reinterpret_cast<const f32x4*>(w + k * 256 + fg * 4);
        wv[k] = v;
        s += fabsf(v.x) + fabsf(v.y) + fabsf(v.z) + fabsf(v.w);
    }
    // wave butterfly: every lane of every wave ends with the identical full sum
#pragma unroll
    for (int m = 1; m < 64; m <<= 1) s += __shfl_xor(s, m, 64);
    const float alpha = s * (1.0f / 4096.0f);
    const float thr = 0.7f * alpha;

    // ---- ternarize in registers ----
#pragma unroll
    for (int k = 0; k < 16; ++k) {
        f32x4 v = wv[k], q;
#pragma unroll
        for (int c = 0; c < 4; ++c) {
            float vc = v[c];
            q[c] = (fabsf(vc) < thr) ? 0.f
                 : (vc > 0.f ? alpha : (vc < 0.f ? -alpha : 0.f));
        }
        wv[k] = q;
    }
    const f32x4 bv = *reinterpret_cast<const f32x4*>(bias + fg * 4);

    __syncthreads();                  // before any store -> free drain

    // rolling 16-wide x window; iter i covers xs[ls+4i .. ls+4i+15]
    float xw[16];
#pragma unroll
    for (int j = 0; j < 16; ++j) xw[j] = xs[ls + j];

    f32x4* outp = reinterpret_cast<f32x4*>(y) + ((size_t)b * L + lbase + ls) * 64 + fg;
#pragma unroll
    for (int i = 0; i < 32; ++i) {
        f32x4 acc = bv;
#pragma unroll
        for (int k = 0; k < 16; ++k) {
            acc += wv[k] * xw[k];
        }
        *outp = acc;
        outp += 256;                  // l += 4
        if (i < 31) {
#pragma unroll
            for (int j = 0; j < 12; ++j) xw[j] = xw[j + 4];
#pragma unroll
            for (int j = 12; j < 16; ++j) xw[j] = xs[ls + 4 * (i + 1) + j];
        }
    }
}

extern "C" void kernel_launch(void* const* d_in, const int* in_sizes, int n_in,
                              void* d_out, int out_size, void* d_ws, size_t ws_size,
                              hipStream_t stream) {
    const float* x = (const float*)d_in[0];   // (32, 8192, 1)
    const float* w = (const float*)d_in[1];   // (16, 1, 256)
    const float* b = (const float*)d_in[2];   // (256,)
    float* y = (float*)d_out;                 // (32, 8192, 256)

    const int B = 32;
    const int L = in_sizes[0] / B;            // 8192

    ternary_conv1d_fused<<<B * 64, 256, 0, stream>>>(x, w, b, y, L);
}

// Round 7
// 51.506 us; speedup vs baseline: 1.0101x; 1.0101x over previous
//
#include <hip/hip_runtime.h>
#include <hip/hip_bf16.h>

typedef float f32x4 __attribute__((ext_vector_type(4)));

// Fully fused ternary-quant + conv1d, barrier-minimal, occupancy-bounded.
// y[b,l,f] = bias[f] + sum_k wq[k,f] * x[b, l+k-7]   (SAME pad: lo=7, hi=8)
// Grid 2048 = 32 b x 64 l-groups: each block owns 128 consecutive l.
// Thread t: fg = t&63 owns f = 4*fg..4*fg+3 (f32x4 stores, plain — nt was -16%),
// ls = t>>6 staggers l (wave-uniform -> LDS broadcast reads).
// __launch_bounds__(256,4): min 4 waves/SIMD -> VGPR capped at 128 (static need
// ~114: wv 64 + xw 16 + acc/addr/misc ~34). Unroll-4 keeps live ranges small.
// alpha: per-wave butterfly (bit-identical across waves), no LDS reduce.
__global__ __launch_bounds__(256, 4) void ternary_conv1d_fused(
    const float* __restrict__ x,   // (B, L)
    const float* __restrict__ w,   // (16, 256) raw
    const float* __restrict__ bias,// (256)
    float* __restrict__ y,         // (B, L, 256)
    int L) {
    const int t  = threadIdx.x;
    const int fg = t & 63;
    const int ls = t >> 6;
    const int bid = blockIdx.x;
    const int b  = bid >> 6;          // 64 l-groups per batch
    const int g  = bid & 63;
    const int lbase = g * 128;

    __shared__ float xs[144];         // xs[j] = x[b, lbase-7+j], j=0..142

    // ---- stage x window ----
    if (t < 143) {
        int gl = lbase - 7 + t;
        xs[t] = (gl >= 0 && gl < L) ? x[(size_t)b * L + gl] : 0.f;
    }

    // ---- load weights + per-lane |w| partial ----
    f32x4 wv[16];
    float s = 0.f;
#pragma unroll
    for (int k = 0; k < 16; ++k) {
        f32x4 v = *reinterpret_cast<const f32x4*>(w + k * 256 + fg * 4);
        wv[k] = v;
        s += fabsf(v.x) + fabsf(v.y) + fabsf(v.z) + fabsf(v.w);
    }
    // wave butterfly: identical full sum in every lane of every wave
#pragma unroll
    for (int m = 1; m < 64; m <<= 1) s += __shfl_xor(s, m, 64);
    const float alpha = s * (1.0f / 4096.0f);
    const float thr = 0.7f * alpha;

    // ---- ternarize in registers ----
#pragma unroll
    for (int k = 0; k < 16; ++k) {
        f32x4 v = wv[k], q;
#pragma unroll
        for (int c = 0; c < 4; ++c) {
            float vc = v[c];
            q[c] = (fabsf(vc) < thr) ? 0.f
                 : (vc > 0.f ? alpha : (vc < 0.f ? -alpha : 0.f));
        }
        wv[k] = q;
    }
    const f32x4 bv = *reinterpret_cast<const f32x4*>(bias + fg * 4);

    __syncthreads();                  // before any store -> free drain

    // rolling 16-wide x window; iter i covers xs[ls+4i .. ls+4i+15]
    float xw[16];
#pragma unroll
    for (int j = 0; j < 16; ++j) xw[j] = xs[ls + j];

    f32x4* outp = reinterpret_cast<f32x4*>(y) + ((size_t)b * L + lbase + ls) * 64 + fg;
#pragma unroll 4
    for (int i = 0; i < 32; ++i) {
        f32x4 acc = bv;
#pragma unroll
        for (int k = 0; k < 16; ++k) {
            acc += wv[k] * xw[k];
        }
        *outp = acc;
        outp += 256;                  // l += 4
        if (i < 31) {
#pragma unroll
            for (int j = 0; j < 12; ++j) xw[j] = xw[j + 4];
#pragma unroll
            for (int j = 12; j < 16; ++j) xw[j] = xs[ls + 4 * (i + 1) + j];
        }
    }
}

extern "C" void kernel_launch(void* const* d_in, const int* in_sizes, int n_in,
                              void* d_out, int out_size, void* d_ws, size_t ws_size,
                              hipStream_t stream) {
    const float* x = (const float*)d_in[0];   // (32, 8192, 1)
    const float* w = (const float*)d_in[1];   // (16, 1, 256)
    const float* b = (const float*)d_in[2];   // (256,)
    float* y = (float*)d_out;                 // (32, 8192, 256)

    const int B = 32;
    const int L = in_sizes[0] / B;            // 8192

    ternary_conv1d_fused<<<B * 64, 256, 0, stream>>>(x, w, b, y, L);
}

// Round 8
// 50.687 us; speedup vs baseline: 1.0265x; 1.0162x over previous
//
#include <hip/hip_runtime.h>
#include <hip/hip_bf16.h>

typedef float f32x4 __attribute__((ext_vector_type(4)));

// Fully fused ternary-quant + conv1d.
// y[b,l,f] = bias[f] + sum_k wq[k,f] * x[b, l+k-7]   (SAME pad: lo=7, hi=8)
// Grid 2048 = 32 b x 64 l-groups: block owns 128 consecutive l.
// NEW (R8): wave ls owns a CONTIGUOUS 32-l range [lbase+32ls, +32) -> each
// wave's store stream is sequential 1KB chunks (was 4KB-strided; testing DRAM
// write-locality theory). Thread t: fg = t&63 owns f = 4*fg..4*fg+3 (f32x4
// stores, plain — nt was -16%). Window slides 1 l/iter: 1 LDS broadcast/iter.
// alpha: per-wave butterfly (bit-identical across waves), no LDS reduce.
__global__ __launch_bounds__(256, 4) void ternary_conv1d_fused(
    const float* __restrict__ x,   // (B, L)
    const float* __restrict__ w,   // (16, 256) raw
    const float* __restrict__ bias,// (256)
    float* __restrict__ y,         // (B, L, 256)
    int L) {
    const int t  = threadIdx.x;
    const int fg = t & 63;
    const int ls = t >> 6;            // wave id 0..3
    const int bid = blockIdx.x;
    const int b  = bid >> 6;          // 64 l-groups per batch
    const int g  = bid & 63;
    const int lbase = g * 128;

    __shared__ float xs[144];         // xs[j] = x[b, lbase-7+j], j=0..142

    // ---- stage x window ----
    if (t < 143) {
        int gl = lbase - 7 + t;
        xs[t] = (gl >= 0 && gl < L) ? x[(size_t)b * L + gl] : 0.f;
    }

    // ---- load weights + per-lane |w| partial ----
    f32x4 wv[16];
    float s = 0.f;
#pragma unroll
    for (int k = 0; k < 16; ++k) {
        f32x4 v = *reinterpret_cast<const f32x4*>(w + k * 256 + fg * 4);
        wv[k] = v;
        s += fabsf(v.x) + fabsf(v.y) + fabsf(v.z) + fabsf(v.w);
    }
    // wave butterfly: identical full sum in every lane of every wave
#pragma unroll
    for (int m = 1; m < 64; m <<= 1) s += __shfl_xor(s, m, 64);
    const float alpha = s * (1.0f / 4096.0f);
    const float thr = 0.7f * alpha;

    // ---- ternarize in registers ----
#pragma unroll
    for (int k = 0; k < 16; ++k) {
        f32x4 v = wv[k], q;
#pragma unroll
        for (int c = 0; c < 4; ++c) {
            float vc = v[c];
            q[c] = (fabsf(vc) < thr) ? 0.f
                 : (vc > 0.f ? alpha : (vc < 0.f ? -alpha : 0.f));
        }
        wv[k] = q;
    }
    const f32x4 bv = *reinterpret_cast<const f32x4*>(bias + fg * 4);

    __syncthreads();                  // before any store -> free drain

    // rolling 16-wide window; iter i covers xs[32ls+i .. 32ls+i+15]
    float xw[16];
#pragma unroll
    for (int j = 0; j < 16; ++j) xw[j] = xs[ls * 32 + j];

    f32x4* outp = reinterpret_cast<f32x4*>(y)
                + ((size_t)b * L + lbase + ls * 32) * 64 + fg;
#pragma unroll 4
    for (int i = 0; i < 32; ++i) {
        f32x4 acc = bv;
#pragma unroll
        for (int k = 0; k < 16; ++k) {
            acc += wv[k] * xw[k];
        }
        *outp = acc;
        outp += 64;                   // next l: contiguous 1KB stride per wave
        if (i < 31) {
#pragma unroll
            for (int j = 0; j < 15; ++j) xw[j] = xw[j + 1];
            xw[15] = xs[ls * 32 + i + 16];
        }
    }
}

extern "C" void kernel_launch(void* const* d_in, const int* in_sizes, int n_in,
                              void* d_out, int out_size, void* d_ws, size_t ws_size,
                              hipStream_t stream) {
    const float* x = (const float*)d_in[0];   // (32, 8192, 1)
    const float* w = (const float*)d_in[1];   // (16, 1, 256)
    const float* b = (const float*)d_in[2];   // (256,)
    float* y = (float*)d_out;                 // (32, 8192, 256)

    const int B = 32;
    const int L = in_sizes[0] / B;            // 8192

    ternary_conv1d_fused<<<B * 64, 256, 0, stream>>>(x, w, b, y, L);
}

// Round 9
// 48.870 us; speedup vs baseline: 1.0646x; 1.0372x over previous
//
#include <hip/hip_runtime.h>
#include <hip/hip_bf16.h>

typedef float f32x4 __attribute__((ext_vector_type(4)));

// Fully fused ternary-quant + conv1d, persistent blocks.
// y[b,l,f] = bias[f] + sum_k wq[k,f] * x[b, l+k-7]   (SAME pad: lo=7, hi=8)
// Grid 1024 = 32 b x 32 groups (4 blocks/CU, ALL resident, one prologue each):
// block owns 256 consecutive l = two 128-l tiles; both x windows staged in the
// prologue (xs0/xs1), single barrier BEFORE first store, then 512 stores
// stream uninterrupted. Wave ls owns contiguous 32-l per tile. Thread t:
// fg = t&63 owns f = 4*fg..4*fg+3 (plain f32x4 stores — nt was -16%).
// alpha: per-wave butterfly (bit-identical across waves), no LDS reduce.
__global__ __launch_bounds__(256, 4) void ternary_conv1d_fused(
    const float* __restrict__ x,   // (B, L)
    const float* __restrict__ w,   // (16, 256) raw
    const float* __restrict__ bias,// (256)
    float* __restrict__ y,         // (B, L, 256)
    int L) {
    const int t  = threadIdx.x;
    const int fg = t & 63;
    const int ls = t >> 6;            // wave id 0..3
    const int bid = blockIdx.x;
    const int b  = bid >> 5;          // 32 groups per batch
    const int g  = bid & 31;
    const int lbase = g * 256;

    __shared__ float xs0[144];        // x[b, lbase-7   + j], j=0..142 (tile0)
    __shared__ float xs1[144];        // x[b, lbase+121 + j], j=0..142 (tile1)

    // ---- stage both x windows (286 loads over 256 threads) ----
    const size_t xb = (size_t)b * L;
#pragma unroll
    for (int j = t; j < 286; j += 256) {
        int gl = (j < 143) ? (lbase - 7 + j) : (lbase + 121 + (j - 143));
        float v = (gl >= 0 && gl < L) ? x[xb + gl] : 0.f;
        if (j < 143) xs0[j] = v; else xs1[j - 143] = v;
    }

    // ---- load weights + per-lane |w| partial ----
    f32x4 wv[16];
    float s = 0.f;
#pragma unroll
    for (int k = 0; k < 16; ++k) {
        f32x4 v = *reinterpret_cast<const f32x4*>(w + k * 256 + fg * 4);
        wv[k] = v;
        s += fabsf(v.x) + fabsf(v.y) + fabsf(v.z) + fabsf(v.w);
    }
    // wave butterfly: identical full sum in every lane of every wave
#pragma unroll
    for (int m = 1; m < 64; m <<= 1) s += __shfl_xor(s, m, 64);
    const float alpha = s * (1.0f / 4096.0f);
    const float thr = 0.7f * alpha;

    // ---- ternarize in registers ----
#pragma unroll
    for (int k = 0; k < 16; ++k) {
        f32x4 v = wv[k], q;
#pragma unroll
        for (int c = 0; c < 4; ++c) {
            float vc = v[c];
            q[c] = (fabsf(vc) < thr) ? 0.f
                 : (vc > 0.f ? alpha : (vc < 0.f ? -alpha : 0.f));
        }
        wv[k] = q;
    }
    const f32x4 bv = *reinterpret_cast<const f32x4*>(bias + fg * 4);

    __syncthreads();                  // single barrier, before any store

    float xw[16];
    f32x4* outp;

    // ---- tile 0: wave ls stores l in [lbase+32ls, +32), contiguous 1KB/iter ----
#pragma unroll
    for (int j = 0; j < 16; ++j) xw[j] = xs0[ls * 32 + j];
    outp = reinterpret_cast<f32x4*>(y) + ((size_t)b * L + lbase + ls * 32) * 64 + fg;
#pragma unroll 4
    for (int i = 0; i < 32; ++i) {
        f32x4 acc = bv;
#pragma unroll
        for (int k = 0; k < 16; ++k) acc += wv[k] * xw[k];
        *outp = acc;
        outp += 64;
        if (i < 31) {
#pragma unroll
            for (int j = 0; j < 15; ++j) xw[j] = xw[j + 1];
            xw[15] = xs0[ls * 32 + i + 16];
        }
    }

    // ---- tile 1: l in [lbase+128+32ls, +32); xs1 idx = l - (lbase+121) ----
#pragma unroll
    for (int j = 0; j < 16; ++j) xw[j] = xs1[ls * 32 + j];
    outp = reinterpret_cast<f32x4*>(y) + ((size_t)b * L + lbase + 128 + ls * 32) * 64 + fg;
#pragma unroll 4
    for (int i = 0; i < 32; ++i) {
        f32x4 acc = bv;
#pragma unroll
        for (int k = 0; k < 16; ++k) acc += wv[k] * xw[k];
        *outp = acc;
        outp += 64;
        if (i < 31) {
#pragma unroll
            for (int j = 0; j < 15; ++j) xw[j] = xw[j + 1];
            xw[15] = xs1[ls * 32 + i + 16];
        }
    }
}

extern "C" void kernel_launch(void* const* d_in, const int* in_sizes, int n_in,
                              void* d_out, int out_size, void* d_ws, size_t ws_size,
                              hipStream_t stream) {
    const float* x = (const float*)d_in[0];   // (32, 8192, 1)
    const float* w = (const float*)d_in[1];   // (16, 1, 256)
    const float* b = (const float*)d_in[2];   // (256,)
    float* y = (float*)d_out;                 // (32, 8192, 256)

    const int B = 32;
    const int L = in_sizes[0] / B;            // 8192

    ternary_conv1d_fused<<<B * 32, 256, 0, stream>>>(x, w, b, y, L);
}